// Round 1
// 117.644 us; speedup vs baseline: 1.0164x; 1.0164x over previous
//
#include <hip/hip_runtime.h>
#include <hip/hip_fp16.h>

// Reverb via FFT overlap-save cross-correlation. R15 = R14 (119.6us) with
// fwd3_spectral + inv1 FUSED into mid_spectral_inv1 (7 -> 6 dispatches):
//   Key identity: for real h, the packed-real unpacking is unnecessary --
//     B[k] = conj(A[k]*conj(H[k]))/L = conj(A[k])*H[k]/L   (pointwise!)
//   (X0 + i*X1 == A exactly; the mirror terms cancel.) So the spectral
//   multiply needs no mirror exchange, no XS LDS, no 257-block redundancy.
//   The fwd-final dft16 at column gmid = g + 4096*i yields P[g + 4096*(i+16r)]
//   == exactly the m = i+16q register set inv1's group-g thread-i wants, so
//   the inverse first 256-pt stage fuses in with zero data movement.
// Session model: bytes are L2/L3-resident (~free), ~12us/dispatch fixed cost
// dominates; coop sync (~80us), spin sync (~40us) cost more than a host
// boundary. Dispatch count is the lever: 7 slots -> 6 slots.

#define L_FFT (1 << 20)
#define GSTRIDE 273
#define PSCALE (1.0f / 1048576.0f)   // 2^-20 = 1/L (fp16 range; cancels in norm)

__device__ __forceinline__ float2 h2f(__half2 h) { return __half22float2(h); }
__device__ __forceinline__ __half2 f2h(float2 v) { return __floats2half2_rn(v.x, v.y); }

__device__ __forceinline__ float2 cmul(float2 a, float2 b) {
    return make_float2(a.x * b.x - a.y * b.y, a.x * b.y + a.y * b.x);
}

__device__ __forceinline__ void rad4(float2 a, float2 b, float2 c, float2 d,
                                     float2& o0, float2& o1, float2& o2, float2& o3) {
    float2 apc = make_float2(a.x + c.x, a.y + c.y);
    float2 amc = make_float2(a.x - c.x, a.y - c.y);
    float2 bpd = make_float2(b.x + d.x, b.y + d.y);
    float2 bmd = make_float2(b.x - d.x, b.y - d.y);
    o0 = make_float2(apc.x + bpd.x, apc.y + bpd.y);
    o2 = make_float2(apc.x - bpd.x, apc.y - bpd.y);
    o1 = make_float2(amc.x + bmd.y, amc.y - bmd.x);
    o3 = make_float2(amc.x - bmd.y, amc.y + bmd.x);
}

// 16-pt DFT, natural order in/out (bench-verified R2-R14).
__device__ __forceinline__ void dft16(float2 x[16]) {
    float2 tt[16];
    rad4(x[0], x[4], x[8],  x[12], tt[0],  tt[1],  tt[2],  tt[3]);
    rad4(x[1], x[5], x[9],  x[13], tt[4],  tt[5],  tt[6],  tt[7]);
    rad4(x[2], x[6], x[10], x[14], tt[8],  tt[9],  tt[10], tt[11]);
    rad4(x[3], x[7], x[11], x[15], tt[12], tt[13], tt[14], tt[15]);
    const float C1 = 0.92387953251128675613f, S1 = 0.38268343236508977173f;
    const float C2 = 0.70710678118654752440f;
    const float2 W1 = make_float2( C1, -S1);
    const float2 W2 = make_float2( C2, -C2);
    const float2 W3 = make_float2( S1, -C1);
    const float2 W6 = make_float2(-C2, -C2);
    const float2 W9 = make_float2(-C1,  S1);
    tt[5]  = cmul(tt[5],  W1);
    tt[6]  = cmul(tt[6],  W2);
    tt[7]  = cmul(tt[7],  W3);
    tt[9]  = cmul(tt[9],  W2);
    tt[10] = make_float2(tt[10].y, -tt[10].x);
    tt[11] = cmul(tt[11], W6);
    tt[13] = cmul(tt[13], W3);
    tt[14] = cmul(tt[14], W6);
    tt[15] = cmul(tt[15], W9);
    rad4(tt[0], tt[4], tt[8],  tt[12], x[0], x[4], x[8],  x[12]);
    rad4(tt[1], tt[5], tt[9],  tt[13], x[1], x[5], x[9],  x[13]);
    rad4(tt[2], tt[6], tt[10], tt[14], x[2], x[6], x[10], x[14]);
    rad4(tt[3], tt[7], tt[11], tt[15], x[3], x[7], x[11], x[15]);
}

// 256-pt FFT across a 16-thread group (strides 273/17 === 1 mod 16:
// bank-pair = gi+row+col -> 4-way b64 floor; R5-verified).
__device__ __forceinline__ void fft256_core(float2 x[16], int i, int gi,
                                            float2* lds) {
    dft16(x);
    float sa, ca;
    __sincosf(-6.28318530717958647692f * (float)i * (1.0f / 256.0f), &sa, &ca);
    float2 w1 = make_float2(ca, sa);
    float2 w = w1;
#pragma unroll
    for (int k1 = 1; k1 < 16; ++k1) {
        x[k1] = cmul(x[k1], w);
        w = cmul(w, w1);
    }
    float2* base = lds + gi * GSTRIDE;
#pragma unroll
    for (int k1 = 0; k1 < 16; ++k1) base[i * 17 + k1] = x[k1];
    __syncthreads();
#pragma unroll
    for (int q1 = 0; q1 < 16; ++q1) x[q1] = base[q1 * 17 + i];
    dft16(x);
}

// Stage twiddle + Stockham scatter for J=256 passes.
__device__ __forceinline__ void stage256_store(float2 x[16], __half2* db,
                                               int g, int i, int J, int log2J,
                                               float invLn) {
    int j = g & (J - 1);
    int np = g >> log2J;
    float base = -6.28318530717958647692f * (float)np * invLn;
    float sa, ca;
    __sincosf(base * (float)i, &sa, &ca);
    float2 w = make_float2(ca, sa);
    __sincosf(base * 16.0f, &sa, &ca);
    float2 w16 = make_float2(ca, sa);
    size_t ob = (size_t)256 * (g - j) + j;
#pragma unroll
    for (int k2 = 0; k2 < 16; ++k2) {
        db[ob + (size_t)(i + 16 * k2) * J] = f2h(cmul(x[k2], w));
        w = cmul(w, w16);
    }
}

// J=1 store, coalesced via LDS (pad e+(e>>8): 4-way b64 floor), then
// block-contiguous window (R9-verified).
__device__ __forceinline__ void store_j1_coalesced(float2 x[16], __half2* db,
                                                   int bx, int gi, int i, int tid,
                                                   float2* lds, float invL) {
    int g = bx * 16 + gi;
    float base = -6.28318530717958647692f * (float)g * invL;
    float sa, ca;
    __sincosf(base * (float)i, &sa, &ca);
    float2 w = make_float2(ca, sa);
    __sincosf(base * 16.0f, &sa, &ca);
    float2 w16 = make_float2(ca, sa);
    __syncthreads();
#pragma unroll
    for (int k2 = 0; k2 < 16; ++k2) {
        int e = 256 * gi + i + 16 * k2;
        lds[e + (e >> 8)] = cmul(x[k2], w);
        w = cmul(w, w16);
    }
    __syncthreads();
    __half2* dwin = db + (size_t)4096 * bx;
#pragma unroll
    for (int c = 0; c < 16; ++c) {
        int e2 = tid + 256 * c;
        dwin[e2] = f2h(lds[e2 + (e2 >> 8)]);
    }
}

// ---- K1: pack + forward J=1 ----
__global__ void fwd1_pack(const float* __restrict__ audio,
                          const float* __restrict__ ir,
                          __half2* __restrict__ dst, int N, int M, int V) {
    __shared__ float2 lds[16 * GSTRIDE];
    int tid = threadIdx.x;
    int gi = tid & 15, i = tid >> 4;
    int bx = blockIdx.x, slot = blockIdx.y;
    int g = bx * 16 + gi;
    __half2* db = dst + (size_t)slot * L_FFT;

    float2 x[16];
#pragma unroll
    for (int q2 = 0; q2 < 16; ++q2) {
        int idx = g + (i + 16 * q2) * (L_FFT / 256);
        float2 v;
        if (slot == 0) {
            v = make_float2(audio[idx], audio[idx + V]);
        } else if (slot == 1) {
            float a2 = (idx + 2 * V < N) ? audio[idx + 2 * V] : 0.f;
            float a3 = (idx + 3 * V < N) ? audio[idx + 3 * V] : 0.f;
            v = make_float2(a2, a3);
        } else {
            v = make_float2((idx < M) ? ir[idx] : 0.f, 0.f);
        }
        x[q2] = v;
    }
    fft256_core(x, i, gi, lds);
    store_j1_coalesced(x, db, bx, gi, i, tid, lds, 1.0f / (float)L_FFT);
}

// ---- K2/K4: generic radix-256 pass (J=256) ----
__global__ void stage256(const __half2* __restrict__ src, __half2* __restrict__ dst,
                         int J, int log2J, float invLn) {
    __shared__ float2 lds[16 * GSTRIDE];
    int tid = threadIdx.x;
    int gi = tid & 15, i = tid >> 4;
    int g = blockIdx.x * 16 + gi;
    size_t boff = (size_t)blockIdx.y * L_FFT;
    const __half2* sb = src + boff;
    __half2* db = dst + boff;
    float2 x[16];
#pragma unroll
    for (int q2 = 0; q2 < 16; ++q2)
        x[q2] = h2f(sb[g + (i + 16 * q2) * (L_FFT / 256)]);
    fft256_core(x, i, gi, lds);
    stage256_store(x, db, g, i, J, log2J, invLn);
}

// ---- K3: FUSED fwd final radix-16 + spectral multiply + inverse J=1 ----
// Identity (real h): B[k] = conj(A[k])*H[k]/L -- pointwise, no mirror pairing.
// Thread (gi,i) of block bx owns fwd column gmid = g + 4096*i (g = bx*16+gi),
// computes X_A[gmid + 65536r] and H[gmid + 65536r] via dft16 (H recomputed per
// block: VALU is free here), multiplies, and the resulting P registers are
// exactly the m = i+16q lanes of inverse transform g -> fft256_core +
// store_j1_coalesced drop in unchanged (same output convention as old inv1).
__global__ void mid_spectral_inv1(const __half2* __restrict__ A,
                                  __half2* __restrict__ B) {
    __shared__ float2 lds[16 * GSTRIDE];
    int tid = threadIdx.x;
    int gi = tid & 15, i = tid >> 4;
    int bx = blockIdx.x;
    size_t boff = (size_t)blockIdx.y * L_FFT;
    int g = bx * 16 + gi;            // inverse-stage transform index in [0,4096)
    int gmid = g + (i << 12);        // fwd final-stage column in [0,65536)

    const __half2* sa = A + boff;
    const __half2* sh = A + (size_t)2 * L_FFT;
    float2 x[16], h[16];
#pragma unroll
    for (int q = 0; q < 16; ++q) {
        x[q] = h2f(sa[gmid + (size_t)q * 65536]);
        h[q] = h2f(sh[gmid + (size_t)q * 65536]);
    }
    dft16(x);
    dft16(h);
#pragma unroll
    for (int r = 0; r < 16; ++r) {
        float2 Z = x[r], H = h[r];
        // conj(Z)*H / L  (stored conjugated spectrum -> fwd-FFT chain = IFFT)
        x[r] = make_float2((Z.x * H.x + Z.y * H.y) * PSCALE,
                           (Z.x * H.y - Z.y * H.x) * PSCALE);
    }
    fft256_core(x, i, gi, lds);
    store_j1_coalesced(x, B + boff, bx, gi, i, tid, lds, 1.0f / (float)L_FFT);
}

// ---- K5: inverse final radix-16, MAX ONLY (no output write) ----
__global__ void inv3_max(const __half2* __restrict__ src,
                         float* __restrict__ partials, int N, int V) {
    int g = blockIdx.x * blockDim.x + threadIdx.x;
    int p = blockIdx.y;
    const __half2* sb = src + (size_t)p * L_FFT;
    float2 x[16];
#pragma unroll
    for (int q = 0; q < 16; ++q) x[q] = h2f(sb[g + q * 65536]);
    dft16(x);
    int lenO = (p == 1) ? (N - 3 * V) : V;
    float m = 0.f;
#pragma unroll
    for (int r = 0; r < 16; ++r) {
        int n = g + r * 65536;
        if (n < V)    m = fmaxf(m, fabsf(x[r].x));
        if (n < lenO) m = fmaxf(m, fabsf(x[r].y));
    }
    for (int o = 32; o > 0; o >>= 1) m = fmaxf(m, __shfl_xor(m, o));
    __shared__ float sm[4];
    int lane = threadIdx.x & 63, wv = threadIdx.x >> 6;
    if (lane == 0) sm[wv] = m;
    __syncthreads();
    if (threadIdx.x == 0)
        partials[blockIdx.y * gridDim.x + blockIdx.x] =
            fmaxf(fmaxf(sm[0], sm[1]), fmaxf(sm[2], sm[3]));
}

// ---- K6: reduce partials, RECOMPUTE identical dft16, write normalized ----
// Loads issued first so the partials reduction hides their latency (G7).
__global__ void norm_final(const __half2* __restrict__ src,
                           float* __restrict__ out,
                           const float* __restrict__ partials, int N, int V) {
    __shared__ float sm[4];
    int tid = threadIdx.x;
    int g = blockIdx.x * blockDim.x + tid;
    int p = blockIdx.y;
    const __half2* sb = src + (size_t)p * L_FFT;
    float2 x[16];
#pragma unroll
    for (int q = 0; q < 16; ++q) x[q] = h2f(sb[g + q * 65536]);

    float m = 0.f;
    for (int i = tid; i < 512; i += 256) m = fmaxf(m, partials[i]);
    for (int o = 32; o > 0; o >>= 1) m = fmaxf(m, __shfl_xor(m, o));
    int lane = tid & 63, wv = tid >> 6;
    if (lane == 0) sm[wv] = m;
    __syncthreads();
    float inv = 1.0f / fmaxf(fmaxf(sm[0], sm[1]), fmaxf(sm[2], sm[3]));

    dft16(x);   // bit-identical to inv3_max's values (same fp16 input)
    int se = 2 * p, so = 2 * p + 1;
    int lenO = (p == 1) ? (N - 3 * V) : V;
#pragma unroll
    for (int r = 0; r < 16; ++r) {
        int n = g + r * 65536;
        if (n < V)    out[(size_t)se * V + n] = x[r].x * inv;
        if (n < lenO) out[(size_t)so * V + n] = -x[r].y * inv;
    }
}

extern "C" void kernel_launch(void* const* d_in, const int* in_sizes, int n_in,
                              void* d_out, int out_size, void* d_ws, size_t ws_size,
                              hipStream_t stream) {
    const float* audio = (const float*)d_in[0];
    const float* ir    = (const float*)d_in[1];
    float* out = (float*)d_out;

    const int N = in_sizes[0];          // 2,646,000
    const int M = in_sizes[1];          // 220,500
    const int V = L_FFT - M + 1;        // 828,077

    __half2* A = (__half2*)d_ws;                       // 3L half2
    __half2* B = A + (size_t)3 * L_FFT;                // 3L half2
    float* partials = (float*)(B + (size_t)3 * L_FFT); // 512 floats

    const float invLn2 = 1.0f / 4096.0f;

    fwd1_pack<<<dim3(256, 3), 256, 0, stream>>>(audio, ir, B, N, M, V);
    stage256<<<dim3(256, 3), 256, 0, stream>>>(B, A, 256, 8, invLn2);
    mid_spectral_inv1<<<dim3(256, 2), 256, 0, stream>>>(A, B);
    stage256<<<dim3(256, 2), 256, 0, stream>>>(B, A, 256, 8, invLn2);
    inv3_max<<<dim3(256, 2), 256, 0, stream>>>(A, partials, N, V);
    norm_final<<<dim3(256, 2), 256, 0, stream>>>(A, out, partials, N, V);
}

// Round 2
// 101.360 us; speedup vs baseline: 1.1796x; 1.1607x over previous
//
#include <hip/hip_runtime.h>
#include <hip/hip_fp16.h>

// Reverb via FFT overlap-save cross-correlation. R16: restructure the FFT as
// 256 x 4096 (was 256 x 256 x 16). The 4096-pt middle stage fits in ONE
// 256-thread block (dft16 + twiddle + LDS redistribute + fft256_core) and is
// distribution-preserving (thread tid holds elements tid+256w in, bins
// tid+256r out), so ONE kernel chains: fwd-final-4096(X) || fwd-final-4096(H)
// -> conj-multiply -> inverse-first-4096(P) entirely in registers/LDS.
// Dispatches: 6 -> 4. Intermediate global round-trips: 4 -> 2.
//   K1 fwd1_pack : pack + 256-pt stage (stride 4096), store BIN-major
//                  Y1[4096*b0 + g] with twiddle e^{-2pi i g*b0/L} (64B segs).
//   K2 fused_mid : per b0-row: fft4096(X), fft4096(H), P=conj(X)*H/L,
//                  fft4096(P), twiddle e^{-2pi i b0*n_a/L}, coalesced store
//                  M'[4096*b0 + n_a].
//   K3 inv_max   : final 256-pt over b0 (fft256_core) + |y| max partials.
//   K4 norm_write: recompute identical fft256_core, write normalized.
// Math: X[b0+256k1] = sum_g S[g;b0] e^{-2pi i g b0/L} e^{-2pi i g k1/4096};
//       y~[n_a+4096 n_b] = sum_b0 [U1[b0;n_a] e^{-2pi i b0 n_a/L}]
//                                 e^{-2pi i b0 n_b/256}.
// Session model update (R15): graph dispatch fixed cost is small; each extra
// dispatch costs its serial floor (drain + reload-stall at ~8 waves/CU).

#define L_FFT (1 << 20)
#define GSTRIDE 273
#define PSCALE (1.0f / 1048576.0f)   // 2^-20 = 1/L (fp16 range; cancels in norm)

__device__ __forceinline__ float2 h2f(__half2 h) { return __half22float2(h); }
__device__ __forceinline__ __half2 f2h(float2 v) { return __floats2half2_rn(v.x, v.y); }

__device__ __forceinline__ float2 cmul(float2 a, float2 b) {
    return make_float2(a.x * b.x - a.y * b.y, a.x * b.y + a.y * b.x);
}

__device__ __forceinline__ void rad4(float2 a, float2 b, float2 c, float2 d,
                                     float2& o0, float2& o1, float2& o2, float2& o3) {
    float2 apc = make_float2(a.x + c.x, a.y + c.y);
    float2 amc = make_float2(a.x - c.x, a.y - c.y);
    float2 bpd = make_float2(b.x + d.x, b.y + d.y);
    float2 bmd = make_float2(b.x - d.x, b.y - d.y);
    o0 = make_float2(apc.x + bpd.x, apc.y + bpd.y);
    o2 = make_float2(apc.x - bpd.x, apc.y - bpd.y);
    o1 = make_float2(amc.x + bmd.y, amc.y - bmd.x);
    o3 = make_float2(amc.x - bmd.y, amc.y + bmd.x);
}

// 16-pt DFT, natural order in/out (bench-verified R2-R15).
__device__ __forceinline__ void dft16(float2 x[16]) {
    float2 tt[16];
    rad4(x[0], x[4], x[8],  x[12], tt[0],  tt[1],  tt[2],  tt[3]);
    rad4(x[1], x[5], x[9],  x[13], tt[4],  tt[5],  tt[6],  tt[7]);
    rad4(x[2], x[6], x[10], x[14], tt[8],  tt[9],  tt[10], tt[11]);
    rad4(x[3], x[7], x[11], x[15], tt[12], tt[13], tt[14], tt[15]);
    const float C1 = 0.92387953251128675613f, S1 = 0.38268343236508977173f;
    const float C2 = 0.70710678118654752440f;
    const float2 W1 = make_float2( C1, -S1);
    const float2 W2 = make_float2( C2, -C2);
    const float2 W3 = make_float2( S1, -C1);
    const float2 W6 = make_float2(-C2, -C2);
    const float2 W9 = make_float2(-C1,  S1);
    tt[5]  = cmul(tt[5],  W1);
    tt[6]  = cmul(tt[6],  W2);
    tt[7]  = cmul(tt[7],  W3);
    tt[9]  = cmul(tt[9],  W2);
    tt[10] = make_float2(tt[10].y, -tt[10].x);
    tt[11] = cmul(tt[11], W6);
    tt[13] = cmul(tt[13], W3);
    tt[14] = cmul(tt[14], W6);
    tt[15] = cmul(tt[15], W9);
    rad4(tt[0], tt[4], tt[8],  tt[12], x[0], x[4], x[8],  x[12]);
    rad4(tt[1], tt[5], tt[9],  tt[13], x[1], x[5], x[9],  x[13]);
    rad4(tt[2], tt[6], tt[10], tt[14], x[2], x[6], x[10], x[14]);
    rad4(tt[3], tt[7], tt[11], tt[15], x[3], x[7], x[11], x[15]);
}

// 256-pt FFT across a 16-thread group: input x[q] = element (i+16q), output
// x[q] = bin (i+16q). Plain DFT-256, no scale. (bench-verified R2-R15)
// NOTE: no trailing sync -- caller must sync before reusing lds.
__device__ __forceinline__ void fft256_core(float2 x[16], int i, int gi,
                                            float2* lds) {
    dft16(x);
    float sa, ca;
    __sincosf(-6.28318530717958647692f * (float)i * (1.0f / 256.0f), &sa, &ca);
    float2 w1 = make_float2(ca, sa);
    float2 w = w1;
#pragma unroll
    for (int k1 = 1; k1 < 16; ++k1) {
        x[k1] = cmul(x[k1], w);
        w = cmul(w, w1);
    }
    float2* base = lds + gi * GSTRIDE;
#pragma unroll
    for (int k1 = 0; k1 < 16; ++k1) base[i * 17 + k1] = x[k1];
    __syncthreads();
#pragma unroll
    for (int q1 = 0; q1 < 16; ++q1) x[q1] = base[q1 * 17 + i];
    dft16(x);
}

// 4096-pt FFT across a 256-thread block: input x[w] = element (tid + 256*w),
// output x[r] = bin (tid + 256*r). Distribution-preserving. Plain DFT-4096.
// Verified structure: with k1 = a + 16d, element g = u + 256w:
//   X[k1] = sum_u [dft16_w(z)[a] * e^{-2pi i u a/4096}] e^{-2pi i u d/256}
// and a+16*i2 == tid after the redistribute (a = tid&15, i2 = tid>>4).
// No trailing sync (ends inside fft256_core).
__device__ __forceinline__ void fft4096_block(float2 x[16], int tid, float2* lds) {
    dft16(x);
    float sa, ca;
    __sincosf(-6.28318530717958647692f * (float)tid * (1.0f / 4096.0f), &sa, &ca);
    float2 w1 = make_float2(ca, sa);
    float2 w = w1;
#pragma unroll
    for (int a = 1; a < 16; ++a) { x[a] = cmul(x[a], w); w = cmul(w, w1); }
#pragma unroll
    for (int a = 0; a < 16; ++a) lds[a * GSTRIDE + tid] = x[a];
    __syncthreads();
    int an = tid & 15, i2 = tid >> 4;
#pragma unroll
    for (int q = 0; q < 16; ++q) x[q] = lds[an * GSTRIDE + i2 + 16 * q];
    __syncthreads();
    fft256_core(x, i2, an, lds);
}

// Pair version: x and h share the two redistribution barriers.
__device__ __forceinline__ void fft4096_pair(float2 x[16], float2 h[16], int tid,
                                             float2* LX, float2* LH) {
    dft16(x);
    dft16(h);
    float sa, ca;
    __sincosf(-6.28318530717958647692f * (float)tid * (1.0f / 4096.0f), &sa, &ca);
    float2 w1 = make_float2(ca, sa);
    float2 w = w1;
#pragma unroll
    for (int a = 1; a < 16; ++a) {
        x[a] = cmul(x[a], w);
        h[a] = cmul(h[a], w);
        w = cmul(w, w1);
    }
#pragma unroll
    for (int a = 0; a < 16; ++a) {
        LX[a * GSTRIDE + tid] = x[a];
        LH[a * GSTRIDE + tid] = h[a];
    }
    __syncthreads();
    int an = tid & 15, i2 = tid >> 4;
#pragma unroll
    for (int q = 0; q < 16; ++q) {
        x[q] = LX[an * GSTRIDE + i2 + 16 * q];
        h[q] = LH[an * GSTRIDE + i2 + 16 * q];
    }
    __syncthreads();
    fft256_core(x, i2, an, LX);
    fft256_core(h, i2, an, LH);   // its internal barrier also fences LX reads
}

// ---- K1: pack + forward 256-pt stage (stride 4096), bin-major store ----
// Y1[4096*b0 + g] = S[g;b0] * e^{-2pi i g*b0/L}.  64B-segment scatter.
__global__ void fwd1_pack(const float* __restrict__ audio,
                          const float* __restrict__ ir,
                          __half2* __restrict__ dst, int N, int M, int V) {
    __shared__ float2 lds[16 * GSTRIDE];
    int tid = threadIdx.x;
    int gi = tid & 15, i = tid >> 4;
    int bx = blockIdx.x, slot = blockIdx.y;
    int g = bx * 16 + gi;
    __half2* db = dst + (size_t)slot * L_FFT;

    float2 x[16];
#pragma unroll
    for (int q2 = 0; q2 < 16; ++q2) {
        int idx = g + (i + 16 * q2) * (L_FFT / 256);
        float2 v;
        if (slot == 0) {
            v = make_float2(audio[idx], audio[idx + V]);
        } else if (slot == 1) {
            float a2 = (idx + 2 * V < N) ? audio[idx + 2 * V] : 0.f;
            float a3 = (idx + 3 * V < N) ? audio[idx + 3 * V] : 0.f;
            v = make_float2(a2, a3);
        } else {
            v = make_float2((idx < M) ? ir[idx] : 0.f, 0.f);
        }
        x[q2] = v;
    }
    fft256_core(x, i, gi, lds);
    // store bins b0 = i+16q with twiddle e^{-2pi i g*b0/L}, bin-major
    float sa, ca;
    float base = -6.28318530717958647692f * (float)g * (1.0f / (float)L_FFT);
    __sincosf(base * (float)i, &sa, &ca);
    float2 w = make_float2(ca, sa);
    __sincosf(base * 16.0f, &sa, &ca);
    float2 w16 = make_float2(ca, sa);
#pragma unroll
    for (int q = 0; q < 16; ++q) {
        db[(size_t)4096 * (i + 16 * q) + g] = f2h(cmul(x[q], w));
        w = cmul(w, w16);
    }
}

// ---- K2: FUSED fwd-final-4096 (X and H) + spectral multiply + inv-first-4096
// Block = one b0-row per slot p. All loads/stores fully coalesced (rows).
__global__ __launch_bounds__(256, 2) void fused_mid(const __half2* __restrict__ Y1,
                                                    __half2* __restrict__ Mp) {
    __shared__ float2 LX[16 * GSTRIDE];
    __shared__ float2 LH[16 * GSTRIDE];
    int tid = threadIdx.x;
    int b0 = blockIdx.x, p = blockIdx.y;
    const __half2* xr = Y1 + (size_t)p * L_FFT + (size_t)4096 * b0;
    const __half2* hr = Y1 + (size_t)2 * L_FFT + (size_t)4096 * b0;
    float2 x[16], h[16];
#pragma unroll
    for (int w = 0; w < 16; ++w) {
        x[w] = h2f(xr[tid + 256 * w]);
        h[w] = h2f(hr[tid + 256 * w]);
    }
    fft4096_pair(x, h, tid, LX, LH);
    // P~ = conj(X)*H / L  (conjugated spectrum -> fwd-DFT chain = IFFT; R15)
#pragma unroll
    for (int r = 0; r < 16; ++r) {
        float2 Z = x[r], H = h[r];
        x[r] = make_float2((Z.x * H.x + Z.y * H.y) * PSCALE,
                           (Z.x * H.y - Z.y * H.x) * PSCALE);
    }
    // inverse first stage: 4096-pt over k1 (in-register/LDS; fences are the
    // internal barriers of fft4096_pair's second fft256_core + fft4096_block)
    fft4096_block(x, tid, LX);
    // twiddle e^{-2pi i b0*n_a/L}, n_a = tid + 256r; coalesced row store
    float sa, ca;
    float base = -6.28318530717958647692f * (float)b0 * (1.0f / (float)L_FFT);
    __sincosf(base * (float)tid, &sa, &ca);
    float2 w = make_float2(ca, sa);
    __sincosf(base * 256.0f, &sa, &ca);
    float2 ws = make_float2(ca, sa);
    __half2* dst = Mp + (size_t)p * L_FFT + (size_t)4096 * b0;
#pragma unroll
    for (int r = 0; r < 16; ++r) {
        dst[tid + 256 * r] = f2h(cmul(x[r], w));
        w = cmul(w, ws);
    }
}

// ---- K3: inverse final 256-pt over b0 + |y| max partials ----
// y~[n_a + 4096 n_b] = sum_b0 M'[b0; n_a] e^{-2pi i b0 n_b/256}.
// n = n_a + 4096*i + 65536*r with n_a = 16bx+gi, bins n_b = i+16r.
__global__ void inv_max(const __half2* __restrict__ Mp,
                        float* __restrict__ partials, int N, int V) {
    __shared__ float2 lds[16 * GSTRIDE];
    int tid = threadIdx.x;
    int gi = tid & 15, i = tid >> 4;
    int bx = blockIdx.x, p = blockIdx.y;
    const __half2* sb = Mp + (size_t)p * L_FFT;
    int na = 16 * bx + gi;
    float2 x[16];
#pragma unroll
    for (int q = 0; q < 16; ++q)
        x[q] = h2f(sb[(size_t)4096 * (i + 16 * q) + na]);
    fft256_core(x, i, gi, lds);
    int nbase = na + 4096 * i;
    int lenO = (p == 1) ? (N - 3 * V) : V;
    float m = 0.f;
#pragma unroll
    for (int r = 0; r < 16; ++r) {
        int n = nbase + r * 65536;
        if (n < V)    m = fmaxf(m, fabsf(x[r].x));
        if (n < lenO) m = fmaxf(m, fabsf(x[r].y));
    }
    for (int o = 32; o > 0; o >>= 1) m = fmaxf(m, __shfl_xor(m, o));
    __shared__ float sm[4];
    int lane = tid & 63, wv = tid >> 6;
    if (lane == 0) sm[wv] = m;
    __syncthreads();
    if (tid == 0)
        partials[blockIdx.y * gridDim.x + blockIdx.x] =
            fmaxf(fmaxf(sm[0], sm[1]), fmaxf(sm[2], sm[3]));
}

// ---- K4: reduce partials, RECOMPUTE identical fft256_core, write normalized.
// Loads issued first so the partials reduction hides their latency (G7).
__global__ void norm_write(const __half2* __restrict__ Mp,
                           float* __restrict__ out,
                           const float* __restrict__ partials, int N, int V) {
    __shared__ float2 lds[16 * GSTRIDE];
    __shared__ float sm[4];
    int tid = threadIdx.x;
    int gi = tid & 15, i = tid >> 4;
    int bx = blockIdx.x, p = blockIdx.y;
    const __half2* sb = Mp + (size_t)p * L_FFT;
    int na = 16 * bx + gi;
    float2 x[16];
#pragma unroll
    for (int q = 0; q < 16; ++q)
        x[q] = h2f(sb[(size_t)4096 * (i + 16 * q) + na]);

    float m = 0.f;
    for (int t = tid; t < 512; t += 256) m = fmaxf(m, partials[t]);
    for (int o = 32; o > 0; o >>= 1) m = fmaxf(m, __shfl_xor(m, o));
    int lane = tid & 63, wv = tid >> 6;
    if (lane == 0) sm[wv] = m;
    __syncthreads();
    float inv = 1.0f / fmaxf(fmaxf(sm[0], sm[1]), fmaxf(sm[2], sm[3]));

    fft256_core(x, i, gi, lds);   // bit-identical to inv_max (same fp16 input)
    int nbase = na + 4096 * i;
    int se = 2 * p, so = 2 * p + 1;
    int lenO = (p == 1) ? (N - 3 * V) : V;
#pragma unroll
    for (int r = 0; r < 16; ++r) {
        int n = nbase + r * 65536;
        if (n < V)    out[(size_t)se * V + n] = x[r].x * inv;
        if (n < lenO) out[(size_t)so * V + n] = -x[r].y * inv;
    }
}

extern "C" void kernel_launch(void* const* d_in, const int* in_sizes, int n_in,
                              void* d_out, int out_size, void* d_ws, size_t ws_size,
                              hipStream_t stream) {
    const float* audio = (const float*)d_in[0];
    const float* ir    = (const float*)d_in[1];
    float* out = (float*)d_out;

    const int N = in_sizes[0];          // 2,646,000
    const int M = in_sizes[1];          // 220,500
    const int V = L_FFT - M + 1;        // 828,077

    __half2* A = (__half2*)d_ws;                       // 3L half2 (M' buffer)
    __half2* B = A + (size_t)3 * L_FFT;                // 3L half2 (Y1 buffer)
    float* partials = (float*)(B + (size_t)3 * L_FFT); // 512 floats

    fwd1_pack<<<dim3(256, 3), 256, 0, stream>>>(audio, ir, B, N, M, V);
    fused_mid<<<dim3(256, 2), 256, 0, stream>>>(B, A);
    inv_max<<<dim3(256, 2), 256, 0, stream>>>(A, partials, N, V);
    norm_write<<<dim3(256, 2), 256, 0, stream>>>(A, out, partials, N, V);
}

// Round 3
// 100.341 us; speedup vs baseline: 1.1916x; 1.0101x over previous
//
#include <hip/hip_runtime.h>
#include <hip/hip_fp16.h>

// Reverb via FFT overlap-save cross-correlation. R17 = R16 (101.4us) with the
// norm recompute eliminated: K3 (inv_write_max) now writes UNNORMALIZED y
// (fp32) to `out` while computing the max partials -- it already holds every
// value in registers -- and K4 collapses from a full FFT-recompute kernel
// (norm_write: strided loads + dft16 chain + LDS exchange at 2 blocks/CU) to
// a trivial streaming scale (scale_out: 1 float4/thread, no LDS, ~10
// blocks/CU, L3-resident 21MB RMW).
// Structure (4 dispatches, serial chain is irreducible in this paradigm):
//   K1 fwd1_pack    : pack + 256-pt stage (stride 4096), BIN-major store
//                     Y1[4096*b0 + g] * e^{-2pi i g*b0/L} (64B segs).
//   K2 fused_mid    : per b0-row: fft4096(X) || fft4096(H), P=conj(X)*H/L,
//                     fft4096(P), twiddle e^{-2pi i b0*n_a/L}, row store.
//   K3 inv_write_max: final 256-pt over b0 + write unnorm y + max partials.
//   K4 scale_out    : reduce 512 partials, out *= 1/max (float4, in-place).
// Session model: graph dispatch fixed cost small; each dispatch costs its
// serial floor (drain + reload-stall at ~2 blocks/CU for the FFT kernels).
// Spin sync (~40us) / coop sync (~80us) cost more than a boundary -- keep 4.

#define L_FFT (1 << 20)
#define GSTRIDE 273
#define PSCALE (1.0f / 1048576.0f)   // 2^-20 = 1/L (fp16 range; cancels in norm)

__device__ __forceinline__ float2 h2f(__half2 h) { return __half22float2(h); }
__device__ __forceinline__ __half2 f2h(float2 v) { return __floats2half2_rn(v.x, v.y); }

__device__ __forceinline__ float2 cmul(float2 a, float2 b) {
    return make_float2(a.x * b.x - a.y * b.y, a.x * b.y + a.y * b.x);
}

__device__ __forceinline__ void rad4(float2 a, float2 b, float2 c, float2 d,
                                     float2& o0, float2& o1, float2& o2, float2& o3) {
    float2 apc = make_float2(a.x + c.x, a.y + c.y);
    float2 amc = make_float2(a.x - c.x, a.y - c.y);
    float2 bpd = make_float2(b.x + d.x, b.y + d.y);
    float2 bmd = make_float2(b.x - d.x, b.y - d.y);
    o0 = make_float2(apc.x + bpd.x, apc.y + bpd.y);
    o2 = make_float2(apc.x - bpd.x, apc.y - bpd.y);
    o1 = make_float2(amc.x + bmd.y, amc.y - bmd.x);
    o3 = make_float2(amc.x - bmd.y, amc.y + bmd.x);
}

// 16-pt DFT, natural order in/out (bench-verified R2-R16).
__device__ __forceinline__ void dft16(float2 x[16]) {
    float2 tt[16];
    rad4(x[0], x[4], x[8],  x[12], tt[0],  tt[1],  tt[2],  tt[3]);
    rad4(x[1], x[5], x[9],  x[13], tt[4],  tt[5],  tt[6],  tt[7]);
    rad4(x[2], x[6], x[10], x[14], tt[8],  tt[9],  tt[10], tt[11]);
    rad4(x[3], x[7], x[11], x[15], tt[12], tt[13], tt[14], tt[15]);
    const float C1 = 0.92387953251128675613f, S1 = 0.38268343236508977173f;
    const float C2 = 0.70710678118654752440f;
    const float2 W1 = make_float2( C1, -S1);
    const float2 W2 = make_float2( C2, -C2);
    const float2 W3 = make_float2( S1, -C1);
    const float2 W6 = make_float2(-C2, -C2);
    const float2 W9 = make_float2(-C1,  S1);
    tt[5]  = cmul(tt[5],  W1);
    tt[6]  = cmul(tt[6],  W2);
    tt[7]  = cmul(tt[7],  W3);
    tt[9]  = cmul(tt[9],  W2);
    tt[10] = make_float2(tt[10].y, -tt[10].x);
    tt[11] = cmul(tt[11], W6);
    tt[13] = cmul(tt[13], W3);
    tt[14] = cmul(tt[14], W6);
    tt[15] = cmul(tt[15], W9);
    rad4(tt[0], tt[4], tt[8],  tt[12], x[0], x[4], x[8],  x[12]);
    rad4(tt[1], tt[5], tt[9],  tt[13], x[1], x[5], x[9],  x[13]);
    rad4(tt[2], tt[6], tt[10], tt[14], x[2], x[6], x[10], x[14]);
    rad4(tt[3], tt[7], tt[11], tt[15], x[3], x[7], x[11], x[15]);
}

// 256-pt FFT across a 16-thread group: input x[q] = element (i+16q), output
// x[q] = bin (i+16q). Plain DFT-256, no scale. No trailing sync.
__device__ __forceinline__ void fft256_core(float2 x[16], int i, int gi,
                                            float2* lds) {
    dft16(x);
    float sa, ca;
    __sincosf(-6.28318530717958647692f * (float)i * (1.0f / 256.0f), &sa, &ca);
    float2 w1 = make_float2(ca, sa);
    float2 w = w1;
#pragma unroll
    for (int k1 = 1; k1 < 16; ++k1) {
        x[k1] = cmul(x[k1], w);
        w = cmul(w, w1);
    }
    float2* base = lds + gi * GSTRIDE;
#pragma unroll
    for (int k1 = 0; k1 < 16; ++k1) base[i * 17 + k1] = x[k1];
    __syncthreads();
#pragma unroll
    for (int q1 = 0; q1 < 16; ++q1) x[q1] = base[q1 * 17 + i];
    dft16(x);
}

// 4096-pt FFT across a 256-thread block: input x[w] = element (tid + 256*w),
// output x[r] = bin (tid + 256*r). Distribution-preserving. No trailing sync.
__device__ __forceinline__ void fft4096_block(float2 x[16], int tid, float2* lds) {
    dft16(x);
    float sa, ca;
    __sincosf(-6.28318530717958647692f * (float)tid * (1.0f / 4096.0f), &sa, &ca);
    float2 w1 = make_float2(ca, sa);
    float2 w = w1;
#pragma unroll
    for (int a = 1; a < 16; ++a) { x[a] = cmul(x[a], w); w = cmul(w, w1); }
#pragma unroll
    for (int a = 0; a < 16; ++a) lds[a * GSTRIDE + tid] = x[a];
    __syncthreads();
    int an = tid & 15, i2 = tid >> 4;
#pragma unroll
    for (int q = 0; q < 16; ++q) x[q] = lds[an * GSTRIDE + i2 + 16 * q];
    __syncthreads();
    fft256_core(x, i2, an, lds);
}

// Pair version: x and h share the two redistribution barriers.
__device__ __forceinline__ void fft4096_pair(float2 x[16], float2 h[16], int tid,
                                             float2* LX, float2* LH) {
    dft16(x);
    dft16(h);
    float sa, ca;
    __sincosf(-6.28318530717958647692f * (float)tid * (1.0f / 4096.0f), &sa, &ca);
    float2 w1 = make_float2(ca, sa);
    float2 w = w1;
#pragma unroll
    for (int a = 1; a < 16; ++a) {
        x[a] = cmul(x[a], w);
        h[a] = cmul(h[a], w);
        w = cmul(w, w1);
    }
#pragma unroll
    for (int a = 0; a < 16; ++a) {
        LX[a * GSTRIDE + tid] = x[a];
        LH[a * GSTRIDE + tid] = h[a];
    }
    __syncthreads();
    int an = tid & 15, i2 = tid >> 4;
#pragma unroll
    for (int q = 0; q < 16; ++q) {
        x[q] = LX[an * GSTRIDE + i2 + 16 * q];
        h[q] = LH[an * GSTRIDE + i2 + 16 * q];
    }
    __syncthreads();
    fft256_core(x, i2, an, LX);
    fft256_core(h, i2, an, LH);   // its internal barrier also fences LX reads
}

// ---- K1: pack + forward 256-pt stage (stride 4096), bin-major store ----
// Y1[4096*b0 + g] = S[g;b0] * e^{-2pi i g*b0/L}.  64B-segment scatter.
__global__ void fwd1_pack(const float* __restrict__ audio,
                          const float* __restrict__ ir,
                          __half2* __restrict__ dst, int N, int M, int V) {
    __shared__ float2 lds[16 * GSTRIDE];
    int tid = threadIdx.x;
    int gi = tid & 15, i = tid >> 4;
    int bx = blockIdx.x, slot = blockIdx.y;
    int g = bx * 16 + gi;
    __half2* db = dst + (size_t)slot * L_FFT;

    float2 x[16];
#pragma unroll
    for (int q2 = 0; q2 < 16; ++q2) {
        int idx = g + (i + 16 * q2) * (L_FFT / 256);
        float2 v;
        if (slot == 0) {
            v = make_float2(audio[idx], audio[idx + V]);
        } else if (slot == 1) {
            float a2 = (idx + 2 * V < N) ? audio[idx + 2 * V] : 0.f;
            float a3 = (idx + 3 * V < N) ? audio[idx + 3 * V] : 0.f;
            v = make_float2(a2, a3);
        } else {
            v = make_float2((idx < M) ? ir[idx] : 0.f, 0.f);
        }
        x[q2] = v;
    }
    fft256_core(x, i, gi, lds);
    // store bins b0 = i+16q with twiddle e^{-2pi i g*b0/L}, bin-major
    float sa, ca;
    float base = -6.28318530717958647692f * (float)g * (1.0f / (float)L_FFT);
    __sincosf(base * (float)i, &sa, &ca);
    float2 w = make_float2(ca, sa);
    __sincosf(base * 16.0f, &sa, &ca);
    float2 w16 = make_float2(ca, sa);
#pragma unroll
    for (int q = 0; q < 16; ++q) {
        db[(size_t)4096 * (i + 16 * q) + g] = f2h(cmul(x[q], w));
        w = cmul(w, w16);
    }
}

// ---- K2: FUSED fwd-final-4096 (X and H) + spectral multiply + inv-first-4096
// Block = one b0-row per slot p. All loads/stores fully coalesced (rows).
__global__ __launch_bounds__(256, 2) void fused_mid(const __half2* __restrict__ Y1,
                                                    __half2* __restrict__ Mp) {
    __shared__ float2 LX[16 * GSTRIDE];
    __shared__ float2 LH[16 * GSTRIDE];
    int tid = threadIdx.x;
    int b0 = blockIdx.x, p = blockIdx.y;
    const __half2* xr = Y1 + (size_t)p * L_FFT + (size_t)4096 * b0;
    const __half2* hr = Y1 + (size_t)2 * L_FFT + (size_t)4096 * b0;
    float2 x[16], h[16];
#pragma unroll
    for (int w = 0; w < 16; ++w) {
        x[w] = h2f(xr[tid + 256 * w]);
        h[w] = h2f(hr[tid + 256 * w]);
    }
    fft4096_pair(x, h, tid, LX, LH);
    // P~ = conj(X)*H / L  (conjugated spectrum -> fwd-DFT chain = IFFT; R15)
#pragma unroll
    for (int r = 0; r < 16; ++r) {
        float2 Z = x[r], H = h[r];
        x[r] = make_float2((Z.x * H.x + Z.y * H.y) * PSCALE,
                           (Z.x * H.y - Z.y * H.x) * PSCALE);
    }
    fft4096_block(x, tid, LX);
    // twiddle e^{-2pi i b0*n_a/L}, n_a = tid + 256r; coalesced row store
    float sa, ca;
    float base = -6.28318530717958647692f * (float)b0 * (1.0f / (float)L_FFT);
    __sincosf(base * (float)tid, &sa, &ca);
    float2 w = make_float2(ca, sa);
    __sincosf(base * 256.0f, &sa, &ca);
    float2 ws = make_float2(ca, sa);
    __half2* dst = Mp + (size_t)p * L_FFT + (size_t)4096 * b0;
#pragma unroll
    for (int r = 0; r < 16; ++r) {
        dst[tid + 256 * r] = f2h(cmul(x[r], w));
        w = cmul(w, ws);
    }
}

// ---- K3: inverse final 256-pt over b0 + write UNNORMALIZED y + max partials
// y~[n_a + 4096 n_b] = sum_b0 M'[b0; n_a] e^{-2pi i b0 n_b/256}.
// n = n_a + 4096*i + 65536*r with n_a = 16bx+gi, bins n_b = i+16r.
__global__ void inv_write_max(const __half2* __restrict__ Mp,
                              float* __restrict__ out,
                              float* __restrict__ partials, int N, int V) {
    __shared__ float2 lds[16 * GSTRIDE];
    int tid = threadIdx.x;
    int gi = tid & 15, i = tid >> 4;
    int bx = blockIdx.x, p = blockIdx.y;
    const __half2* sb = Mp + (size_t)p * L_FFT;
    int na = 16 * bx + gi;
    float2 x[16];
#pragma unroll
    for (int q = 0; q < 16; ++q)
        x[q] = h2f(sb[(size_t)4096 * (i + 16 * q) + na]);
    fft256_core(x, i, gi, lds);
    int nbase = na + 4096 * i;
    int se = 2 * p, so = 2 * p + 1;
    int lenO = (p == 1) ? (N - 3 * V) : V;
    float m = 0.f;
#pragma unroll
    for (int r = 0; r < 16; ++r) {
        int n = nbase + r * 65536;
        if (n < V) {
            out[(size_t)se * V + n] = x[r].x;
            m = fmaxf(m, fabsf(x[r].x));
        }
        if (n < lenO) {
            out[(size_t)so * V + n] = -x[r].y;
            m = fmaxf(m, fabsf(x[r].y));
        }
    }
    for (int o = 32; o > 0; o >>= 1) m = fmaxf(m, __shfl_xor(m, o));
    __shared__ float sm[4];
    int lane = tid & 63, wv = tid >> 6;
    if (lane == 0) sm[wv] = m;
    __syncthreads();
    if (tid == 0)
        partials[blockIdx.y * gridDim.x + blockIdx.x] =
            fmaxf(fmaxf(sm[0], sm[1]), fmaxf(sm[2], sm[3]));
}

// ---- K4: streaming in-place scale: out *= 1/max(partials). ----
// float4 loads issued BEFORE the partials reduction (latency hides under it).
// No LDS FFT, ~10 blocks/CU: duration = L3-resident 21MB RMW + launch floor.
__global__ void scale_out(float* __restrict__ out,
                          const float* __restrict__ partials, int N) {
    __shared__ float sm[4];
    int tid = threadIdx.x;
    size_t base = ((size_t)blockIdx.x * 256 + tid) * 4;
    bool full = (base + 4 <= (size_t)N);
    float4 v = make_float4(0.f, 0.f, 0.f, 0.f);
    if (full) v = *reinterpret_cast<const float4*>(out + base);

    float m = fmaxf(partials[tid], partials[tid + 256]);
    for (int o = 32; o > 0; o >>= 1) m = fmaxf(m, __shfl_xor(m, o));
    int lane = tid & 63, wv = tid >> 6;
    if (lane == 0) sm[wv] = m;
    __syncthreads();
    float inv = 1.0f / fmaxf(fmaxf(sm[0], sm[1]), fmaxf(sm[2], sm[3]));

    if (full) {
        v.x *= inv; v.y *= inv; v.z *= inv; v.w *= inv;
        *reinterpret_cast<float4*>(out + base) = v;
    } else {
        for (size_t j = base; j < (size_t)N; ++j) out[j] *= inv;
    }
}

extern "C" void kernel_launch(void* const* d_in, const int* in_sizes, int n_in,
                              void* d_out, int out_size, void* d_ws, size_t ws_size,
                              hipStream_t stream) {
    const float* audio = (const float*)d_in[0];
    const float* ir    = (const float*)d_in[1];
    float* out = (float*)d_out;

    const int N = in_sizes[0];          // 2,646,000
    const int M = in_sizes[1];          // 220,500
    const int V = L_FFT - M + 1;        // 828,077

    __half2* A = (__half2*)d_ws;                       // 3L half2 (M' buffer)
    __half2* B = A + (size_t)3 * L_FFT;                // 3L half2 (Y1 buffer)
    float* partials = (float*)(B + (size_t)3 * L_FFT); // 512 floats

    fwd1_pack<<<dim3(256, 3), 256, 0, stream>>>(audio, ir, B, N, M, V);
    fused_mid<<<dim3(256, 2), 256, 0, stream>>>(B, A);
    inv_write_max<<<dim3(256, 2), 256, 0, stream>>>(A, out, partials, N, V);
    const int nblk = (N / 4 + 255) / 256;              // 1 float4 per thread
    scale_out<<<dim3(nblk), 256, 0, stream>>>(out, partials, N);
}